// Round 4
// baseline (92.045 us; speedup 1.0000x reference)
//
#include <hip/hip_runtime.h>

#define HOP 512
#define MAX_NHAR 128
#define N_MAX 4410
#define ROWP 4416               // N_MAX rounded up to x8; rows zero-padded to here
#define SEGS 8
#define PI_D 3.14159265358979323846

// ---------------------------------------------------------------------------
// Frame-parameter computation (bit-exact vs reference; absmax 0.0 since R1).
// ---------------------------------------------------------------------------
__device__ __forceinline__ void frame_params(double f0v, int& w, int& nhar, double& theta) {
    double f0d = f0v < 40.0 ? 40.0 : f0v;
    const double inv = 44100.0 / f0d;
    nhar = (int)fmin(floor(inv * 0.5), 128.0);
    w = 2 * (int)rint(inv * 2.0);
    if (w > N_MAX) w = N_MAX;
    theta = (2.0 * PI_D * f0d) / 44100.0;
}

__device__ __forceinline__ int chunk8_of(int w) {
    return (((w + SEGS - 1) / SEGS) + 7) & ~7;   // per-segment span, multiple of 8
}

// ---------------------------------------------------------------------------
// Kernel A: per-frame prep. (1) cos table C[f][k]=cos(theta (k+1)).
// (2) Blackman-windowed frame -> global row xw[f][0..ROWP), zeros beyond w.
// Window via R1's rotating-phasor recurrence (verified absmax 0.0).
// ---------------------------------------------------------------------------
__global__ __launch_bounds__(128) void prep_kernel(
    const float* __restrict__ x, const float* __restrict__ f0,
    double* __restrict__ ccos, double* __restrict__ xw, int t, int F)
{
    const int f = blockIdx.x, tid = threadIdx.x;
    int w, nhar; double theta;
    frame_params((double)f0[f], w, nhar, theta);
    ccos[f * MAX_NHAR + tid] = cos(theta * (double)(tid + 1));

    const double invw = 1.0 / (double)w;
    double sa, ca, ss, cs;
    sincos((2.0 * PI_D) * ((double)tid * invw), &sa, &ca);
    sincos((2.0 * PI_D) * (128.0 * invw), &ss, &cs);
    double zr = ca, zi = sa;
    const int base = f * HOP - (w >> 1);
    double* row = xw + (size_t)f * ROWP;
    for (int j = tid; j < ROWP; j += 128) {
        double outv = 0.0;
        if (j < w) {
            const int ix = base + j;
            const double val = (ix >= 0 && ix < t) ? (double)x[ix] : 0.0;
            const double c = zr;
            const double win = 0.42 - 0.5 * c + 0.08 * (2.0 * c * c - 1.0);
            outv = val * win;
        }
        row[j] = outv;
        const double nzr = zr * cs - zi * ss;   // advance phasor by e^{i 2pi 128/w}
        zi = zr * ss + zi * cs;
        zr = nzr;
    }
}

// ---------------------------------------------------------------------------
// Kernel B (hot): per (frame,segment) real Goertzel, NO LDS. 64 threads,
// 2 harmonics per lane (k=lane, k+64). Sample addresses are wave-uniform ->
// scalar s_load (or broadcast global_load); either way the LDS pipe that
// limited R3 (~17us of ds_read_b64 serialization) is idle. 4 fp64 VALU ops
// per sample per wave = issue-bound floor ~5.5us across the grid.
// Segments padded to x8 with stored zeros: appending zeros to the sequence
// leaves sum(x z^j) unchanged; finalize rotates by the padded length.
// fp64 throughout: atan2 branch cut makes fp32 drift a 2*pi absmax fail.
// ---------------------------------------------------------------------------
__global__ __launch_bounds__(64) void goertzel_kernel(
    const float* __restrict__ f0, const double* __restrict__ ccos,
    const double* __restrict__ xw, double2* __restrict__ parts, int F)
{
    const int frame = blockIdx.x >> 3;
    const int seg   = blockIdx.x & (SEGS - 1);
    const int lane  = threadIdx.x;          // 0..63

    int w, nhar; double theta;
    frame_params((double)f0[frame], w, nhar, theta);
    const int chunk = chunk8_of(w);
    const int j0 = seg * chunk;
    int lenp = 0;
    if (j0 < w) {
        const int l = w - j0;
        lenp = (l > chunk) ? chunk : ((l + 7) & ~7);   // padded reads stay < ROWP
    }

    const double Ca = 2.0 * ccos[frame * MAX_NHAR + lane];
    const double Cb = 2.0 * ccos[frame * MAX_NHAR + lane + 64];
    double s1a = 0.0, s2a = 0.0, s1b = 0.0, s2b = 0.0;
    const double* __restrict__ row = xw + (size_t)frame * ROWP + j0;

    if (nhar > 64) {
        for (int jb = 0; jb < lenp; jb += 8) {
            double xv[8];
            #pragma unroll
            for (int u = 0; u < 8; ++u) xv[u] = row[jb + u];
            #pragma unroll
            for (int u = 0; u < 8; ++u) {
                const double ta = xv[u] - s2a;
                const double tb = xv[u] - s2b;
                const double na = fma(Ca, s1a, ta);
                const double nb = fma(Cb, s1b, tb);
                s2a = s1a; s1a = na;
                s2b = s1b; s1b = nb;
            }
        }
    } else {
        // harmonics 65..128 all masked for this frame: run stream a only
        for (int jb = 0; jb < lenp; jb += 8) {
            double xv[8];
            #pragma unroll
            for (int u = 0; u < 8; ++u) xv[u] = row[jb + u];
            #pragma unroll
            for (int u = 0; u < 8; ++u) {
                const double ta = xv[u] - s2a;
                const double na = fma(Ca, s1a, ta);
                s2a = s1a; s1a = na;
            }
        }
    }
    double2* p = parts + (size_t)(frame * SEGS + seg) * MAX_NHAR;
    p[lane]      = make_double2(s1a, s2a);
    p[lane + 64] = make_double2(s1b, s2b);
}

// ---------------------------------------------------------------------------
// Kernel C: combine SEGS partials analytically, scale, amp/phase.
// partial_y(seg) = P * (s1 - e^{-iw} s2), P = e^{-iw (j0 + steps - 1)}.
// Mid segs: steps == chunk -> P advances by Q = e^{-iw chunk} (recurrence).
// Last data seg (slast): steps = padded length -> dedicated sincos.
// Segs past slast stored (0,0) -> contribute 0 under any rotation.
// ---------------------------------------------------------------------------
__global__ __launch_bounds__(128) void finalize_kernel(
    const float* __restrict__ f0, const double2* __restrict__ parts,
    float* __restrict__ out, int F)
{
    const int frame = blockIdx.x;
    const int tid = threadIdx.x;

    int w, nhar; double theta;
    frame_params((double)f0[frame], w, nhar, theta);
    const int chunk = chunk8_of(w);
    const int slast = (w - 1) / chunk;
    const int endlast = slast * chunk + (((w - slast * chunk) + 7) & ~7);
    const double omega = theta * (double)(tid + 1);

    double sw, cw; sincos(omega, &sw, &cw);                      // e^{-iw} = (cw,-sw)
    double sq, cq; sincos(omega * (double)chunk, &sq, &cq);      // Q = (cq,-sq)
    double sl, cl; sincos(omega * (double)(endlast - 1), &sl, &cl);

    double Rr = cq * cw + sq * sw, Ri = cq * sw - sq * cw;       // e^{-iw(chunk-1)}
    double yr = 0.0, yi = 0.0;
    const double2* p = parts + (size_t)frame * SEGS * MAX_NHAR + tid;
    #pragma unroll
    for (int s = 0; s < SEGS; ++s) {
        const double2 v = p[(size_t)s * MAX_NHAR];
        const double tr = fma(-cw, v.y, v.x);
        const double ti = sw * v.y;
        const double Pr = (s == slast) ? cl : Rr;
        const double Pi = (s == slast) ? -sl : Ri;
        yr = fma(Pr, tr, fma(-Pi, ti, yr));
        yi = fma(Pr, ti, fma( Pi, tr, yi));
        const double nr = Rr * cq + Ri * sq;                     // R *= Q
        Ri = Ri * cq - Rr * sq; Rr = nr;
    }
    const double scale = 2.381 / (double)((w >> 1) + 1);
    yr *= scale; yi *= scale;

    float ampl = 0.0f, ph = 0.0f;
    if (tid < nhar) {
        ampl = (float)sqrt(yr * yr + yi * yi);
        ph   = (float)atan2(yi, yr);
    }
    out[tid * F + frame] = ampl;
    out[MAX_NHAR * F + tid * F + frame] = ph;
}

// ---------------------------------------------------------------------------
// Fallback: single-kernel direct DFT (R1, verified) if ws is too small.
// ---------------------------------------------------------------------------
__global__ __launch_bounds__(128) void czt_direct_kernel(
    const float* __restrict__ x, const float* __restrict__ f0,
    float* __restrict__ out, int t, int F)
{
    __shared__ double sm[N_MAX];
    const int frame = blockIdx.x;
    const int tid = threadIdx.x;
    int w, nhar; double theta;
    frame_params((double)f0[frame], w, nhar, theta);
    {
        const double invw = 1.0 / (double)w;
        double sa, ca, ss, cs;
        sincos((2.0 * PI_D) * ((double)tid * invw), &sa, &ca);
        sincos((2.0 * PI_D) * (128.0 * invw), &ss, &cs);
        double zr = ca, zi = sa;
        const int base = frame * HOP - (w >> 1);
        for (int j = tid; j < w; j += 128) {
            const int ix = base + j;
            const double val = (ix >= 0 && ix < t) ? (double)x[ix] : 0.0;
            const double c = zr;
            const double win = 0.42 - 0.5 * c + 0.08 * (2.0 * c * c - 1.0);
            sm[j] = val * win;
            const double nzr = zr * cs - zi * ss;
            zi = zr * ss + zi * cs;
            zr = nzr;
        }
    }
    __syncthreads();
    double s, c;
    sincos(theta * (double)(tid + 1), &s, &c);
    const double rr = c, ri = -s;
    const double r2r = rr * rr - ri * ri, r2i = 2.0 * rr * ri;
    const double r4r = r2r * r2r - r2i * r2i, r4i = 2.0 * r2r * r2i;
    const double r3r = r2r * rr - r2i * ri, r3i = r2r * ri + r2i * rr;
    double z0r = 1.0, z0i = 0.0, z1r = rr, z1i = ri;
    double z2r = r2r, z2i = r2i, z3r = r3r, z3i = r3i;
    double a0r = 0, a0i = 0, a1r = 0, a1i = 0, a2r = 0, a2i = 0, a3r = 0, a3i = 0;
    const int w4 = w & ~3;
    for (int j = 0; j < w4; j += 4) {
        const double s0 = sm[j], s1 = sm[j + 1], s2 = sm[j + 2], s3 = sm[j + 3];
        double tr;
        a0r = fma(s0, z0r, a0r); a0i = fma(s0, z0i, a0i);
        tr = z0r * r4r - z0i * r4i; z0i = z0r * r4i + z0i * r4r; z0r = tr;
        a1r = fma(s1, z1r, a1r); a1i = fma(s1, z1i, a1i);
        tr = z1r * r4r - z1i * r4i; z1i = z1r * r4i + z1i * r4r; z1r = tr;
        a2r = fma(s2, z2r, a2r); a2i = fma(s2, z2i, a2i);
        tr = z2r * r4r - z2i * r4i; z2i = z2r * r4i + z2i * r4r; z2r = tr;
        a3r = fma(s3, z3r, a3r); a3i = fma(s3, z3i, a3i);
        tr = z3r * r4r - z3i * r4i; z3i = z3r * r4i + z3i * r4r; z3r = tr;
    }
    if (w4 < w) {
        const double s0 = sm[w4], s1 = sm[w4 + 1];
        a0r = fma(s0, z0r, a0r); a0i = fma(s0, z0i, a0i);
        a1r = fma(s1, z1r, a1r); a1i = fma(s1, z1i, a1i);
    }
    double yr = (a0r + a1r) + (a2r + a3r);
    double yi = (a0i + a1i) + (a2i + a3i);
    const double scale = 2.381 / (double)((w >> 1) + 1);
    yr *= scale; yi *= scale;
    float ampl = 0.0f, ph = 0.0f;
    if (tid < nhar) {
        ampl = (float)sqrt(yr * yr + yi * yi);
        ph   = (float)atan2(yi, yr);
    }
    out[tid * F + frame] = ampl;
    out[MAX_NHAR * F + tid * F + frame] = ph;
}

extern "C" void kernel_launch(void* const* d_in, const int* in_sizes, int n_in,
                              void* d_out, int out_size, void* d_ws, size_t ws_size,
                              hipStream_t stream) {
    const float* x  = (const float*)d_in[0];
    const float* f0 = (const float*)d_in[1];
    float* out = (float*)d_out;
    const int t = in_sizes[0];
    const int F = in_sizes[1];

    const size_t ccos_b  = (size_t)F * MAX_NHAR * sizeof(double);        // 1 MB
    const size_t xw_b    = (size_t)F * ROWP * sizeof(double);            // 36 MB
    const size_t parts_b = (size_t)F * SEGS * MAX_NHAR * sizeof(double2);// 17 MB
    if (ws_size >= ccos_b + xw_b + parts_b) {
        double*  ccos  = (double*)d_ws;
        double*  xw    = (double*)((char*)d_ws + ccos_b);
        double2* parts = (double2*)((char*)d_ws + ccos_b + xw_b);
        prep_kernel<<<F, 128, 0, stream>>>(x, f0, ccos, xw, t, F);
        goertzel_kernel<<<F * SEGS, 64, 0, stream>>>(f0, ccos, xw, parts, F);
        finalize_kernel<<<F, 128, 0, stream>>>(f0, parts, out, F);
    } else {
        czt_direct_kernel<<<F, 128, 0, stream>>>(x, f0, out, t, F);
    }
}

// Round 5
// 83.124 us; speedup vs baseline: 1.1073x; 1.1073x over previous
//
#include <hip/hip_runtime.h>

#define HOP 512
#define MAX_NHAR 128
#define N_MAX 4410
#define SEGS 8
#define CHUNK_MAX 552           // pad8(ceil(N_MAX/SEGS)) -- max per-segment span
#define PI_D 3.14159265358979323846

// ---------------------------------------------------------------------------
// Frame-parameter computation (bit-exact vs reference; absmax 0.0 since R1).
// ---------------------------------------------------------------------------
__device__ __forceinline__ void frame_params(double f0v, int& w, int& nhar, double& theta) {
    double f0d = f0v < 40.0 ? 40.0 : f0v;
    const double inv = 44100.0 / f0d;
    nhar = (int)fmin(floor(inv * 0.5), 128.0);
    w = 2 * (int)rint(inv * 2.0);
    if (w > N_MAX) w = N_MAX;
    theta = (2.0 * PI_D * f0d) / 44100.0;
}

__device__ __forceinline__ int chunk8_of(int w) {
    return (((w + SEGS - 1) / SEGS) + 7) & ~7;   // per-segment span, multiple of 8
}

// ---------------------------------------------------------------------------
// Kernel A: cos table C[f][k] = cos(theta_f (k+1)).  ~0.5us.
// ---------------------------------------------------------------------------
__global__ __launch_bounds__(128) void prep_kernel(
    const float* __restrict__ f0, double* __restrict__ ccos, int F)
{
    const int f = blockIdx.x, k = threadIdx.x;
    int w, nhar; double theta;
    frame_params((double)f0[f], w, nhar, theta);
    ccos[f * MAX_NHAR + k] = cos(theta * (double)(k + 1));
}

// ---------------------------------------------------------------------------
// Kernel B (hot, fused): per (frame,segment) stage + real Goertzel.
// 64 threads = ONE wave; 2 harmonics per lane -> each sample is read from LDS
// exactly once per (frame,sample) [R3 read it twice -> ~16us LDS serialization;
// R4's global-read variant was no cheaper and added a 36MB round-trip].
// Segment padded to x8 with zeros staged into LDS; appending zeros only
// advances the recurrence -- finalize rotates by the padded length (endlast),
// verified absmax 0.0 in R4.
// fp64 throughout: atan2 branch cut at +/-pi makes fp32 drift a 2*pi fail.
// ---------------------------------------------------------------------------
__global__ __launch_bounds__(64) void goertzel_kernel(
    const float* __restrict__ x, const float* __restrict__ f0,
    const double* __restrict__ ccos, double2* __restrict__ parts,
    int t, int F)
{
    __shared__ double sm[CHUNK_MAX];
    const int frame = blockIdx.x >> 3;
    const int seg   = blockIdx.x & (SEGS - 1);
    const int lane  = threadIdx.x;          // 0..63

    int w, nhar; double theta;
    frame_params((double)f0[frame], w, nhar, theta);
    const int chunk = chunk8_of(w);
    const int j0 = seg * chunk;
    int lenp = 0;
    if (j0 < w) {
        const int l = w - j0;
        lenp = (l > chunk) ? chunk : ((l + 7) & ~7);   // padded length (x8)
    }

    // ---- stage Blackman-windowed samples into LDS (direct fp64 cos) ----
    {
        const double c2pi_invw = (2.0 * PI_D) / (double)w;
        const int base = frame * HOP - (w >> 1) + j0;
        for (int j = lane; j < lenp; j += 64) {
            double outv = 0.0;
            if (j0 + j < w) {
                const int ix = base + j;
                const double val = (ix >= 0 && ix < t) ? (double)x[ix] : 0.0;
                const double c1 = cos(c2pi_invw * (double)(j0 + j));
                // 0.42 - 0.5 c + 0.08 (2c^2-1) = 0.34 - 0.5 c + 0.16 c^2
                const double win = fma(0.16, c1 * c1, 0.34) - 0.5 * c1;
                outv = val * win;
            }
            sm[j] = outv;
        }
    }
    __syncthreads();   // single wave: compiles to a cheap waitcnt

    // ---- 2-stream Goertzel: harmonics k=lane and k=lane+64 ----
    const double Ca = 2.0 * ccos[frame * MAX_NHAR + lane];
    const double Cb = 2.0 * ccos[frame * MAX_NHAR + lane + 64];
    double s1a = 0.0, s2a = 0.0, s1b = 0.0, s2b = 0.0;

    if (nhar > 64) {
        for (int jb = 0; jb < lenp; jb += 8) {
            double xv[8];
            #pragma unroll
            for (int u = 0; u < 8; ++u) xv[u] = sm[jb + u];
            #pragma unroll
            for (int u = 0; u < 8; ++u) {
                const double ta = xv[u] - s2a;
                const double tb = xv[u] - s2b;
                const double na = fma(Ca, s1a, ta);
                const double nb = fma(Cb, s1b, tb);
                s2a = s1a; s1a = na;
                s2b = s1b; s1b = nb;
            }
        }
    } else {
        // harmonics 65..128 all masked for this frame: single stream
        for (int jb = 0; jb < lenp; jb += 8) {
            double xv[8];
            #pragma unroll
            for (int u = 0; u < 8; ++u) xv[u] = sm[jb + u];
            #pragma unroll
            for (int u = 0; u < 8; ++u) {
                const double ta = xv[u] - s2a;
                const double na = fma(Ca, s1a, ta);
                s2a = s1a; s1a = na;
            }
        }
    }
    double2* p = parts + (size_t)(frame * SEGS + seg) * MAX_NHAR;
    p[lane]      = make_double2(s1a, s2a);
    p[lane + 64] = make_double2(s1b, s2b);   // zeros when single-stream (masked later)
}

// ---------------------------------------------------------------------------
// Kernel C: combine SEGS partials analytically, scale, amp/phase. (R4-verified)
// partial_y(seg) = P (s1 - e^{-iw} s2), P = e^{-iw (j0 + steps - 1)};
// mid segs steps==chunk -> P advances by Q = e^{-iw chunk}; last data seg
// uses the padded end position (endlast).
// ---------------------------------------------------------------------------
__global__ __launch_bounds__(128) void finalize_kernel(
    const float* __restrict__ f0, const double2* __restrict__ parts,
    float* __restrict__ out, int F)
{
    const int frame = blockIdx.x;
    const int tid = threadIdx.x;

    int w, nhar; double theta;
    frame_params((double)f0[frame], w, nhar, theta);
    const int chunk = chunk8_of(w);
    const int slast = (w - 1) / chunk;       // always 7 for w in [442,4410], but general
    const int endlast = slast * chunk + (((w - slast * chunk) + 7) & ~7);
    const double omega = theta * (double)(tid + 1);

    double sw, cw; sincos(omega, &sw, &cw);                      // e^{-iw} = (cw,-sw)
    double sq, cq; sincos(omega * (double)chunk, &sq, &cq);      // Q = (cq,-sq)
    double sl, cl; sincos(omega * (double)(endlast - 1), &sl, &cl);

    double Rr = cq * cw + sq * sw, Ri = cq * sw - sq * cw;       // e^{-iw(chunk-1)}
    double yr = 0.0, yi = 0.0;
    const double2* p = parts + (size_t)frame * SEGS * MAX_NHAR + tid;
    #pragma unroll
    for (int s = 0; s < SEGS; ++s) {
        const double2 v = p[(size_t)s * MAX_NHAR];
        const double tr = fma(-cw, v.y, v.x);
        const double ti = sw * v.y;
        const double Pr = (s == slast) ? cl : Rr;
        const double Pi = (s == slast) ? -sl : Ri;
        yr = fma(Pr, tr, fma(-Pi, ti, yr));
        yi = fma(Pr, ti, fma( Pi, tr, yi));
        const double nr = Rr * cq + Ri * sq;                     // R *= Q
        Ri = Ri * cq - Rr * sq; Rr = nr;
    }
    const double scale = 2.381 / (double)((w >> 1) + 1);
    yr *= scale; yi *= scale;

    float ampl = 0.0f, ph = 0.0f;
    if (tid < nhar) {
        ampl = (float)sqrt(yr * yr + yi * yi);
        ph   = (float)atan2(yi, yr);
    }
    out[tid * F + frame] = ampl;
    out[MAX_NHAR * F + tid * F + frame] = ph;
}

// ---------------------------------------------------------------------------
// Fallback: single-kernel direct DFT (R1, verified) if ws is too small.
// ---------------------------------------------------------------------------
__global__ __launch_bounds__(128) void czt_direct_kernel(
    const float* __restrict__ x, const float* __restrict__ f0,
    float* __restrict__ out, int t, int F)
{
    __shared__ double sm[N_MAX];
    const int frame = blockIdx.x;
    const int tid = threadIdx.x;
    int w, nhar; double theta;
    frame_params((double)f0[frame], w, nhar, theta);
    {
        const double invw = 1.0 / (double)w;
        double sa, ca, ss, cs;
        sincos((2.0 * PI_D) * ((double)tid * invw), &sa, &ca);
        sincos((2.0 * PI_D) * (128.0 * invw), &ss, &cs);
        double zr = ca, zi = sa;
        const int base = frame * HOP - (w >> 1);
        for (int j = tid; j < w; j += 128) {
            const int ix = base + j;
            const double val = (ix >= 0 && ix < t) ? (double)x[ix] : 0.0;
            const double c = zr;
            const double win = 0.42 - 0.5 * c + 0.08 * (2.0 * c * c - 1.0);
            sm[j] = val * win;
            const double nzr = zr * cs - zi * ss;
            zi = zr * ss + zi * cs;
            zr = nzr;
        }
    }
    __syncthreads();
    double s, c;
    sincos(theta * (double)(tid + 1), &s, &c);
    const double rr = c, ri = -s;
    const double r2r = rr * rr - ri * ri, r2i = 2.0 * rr * ri;
    const double r4r = r2r * r2r - r2i * r2i, r4i = 2.0 * r2r * r2i;
    const double r3r = r2r * rr - r2i * ri, r3i = r2r * ri + r2i * rr;
    double z0r = 1.0, z0i = 0.0, z1r = rr, z1i = ri;
    double z2r = r2r, z2i = r2i, z3r = r3r, z3i = r3i;
    double a0r = 0, a0i = 0, a1r = 0, a1i = 0, a2r = 0, a2i = 0, a3r = 0, a3i = 0;
    const int w4 = w & ~3;
    for (int j = 0; j < w4; j += 4) {
        const double s0 = sm[j], s1 = sm[j + 1], s2 = sm[j + 2], s3 = sm[j + 3];
        double tr;
        a0r = fma(s0, z0r, a0r); a0i = fma(s0, z0i, a0i);
        tr = z0r * r4r - z0i * r4i; z0i = z0r * r4i + z0i * r4r; z0r = tr;
        a1r = fma(s1, z1r, a1r); a1i = fma(s1, z1i, a1i);
        tr = z1r * r4r - z1i * r4i; z1i = z1r * r4i + z1i * r4r; z1r = tr;
        a2r = fma(s2, z2r, a2r); a2i = fma(s2, z2i, a2i);
        tr = z2r * r4r - z2i * r4i; z2i = z2r * r4i + z2i * r4r; z2r = tr;
        a3r = fma(s3, z3r, a3r); a3i = fma(s3, z3i, a3i);
        tr = z3r * r4r - z3i * r4i; z3i = z3r * r4i + z3i * r4r; z3r = tr;
    }
    if (w4 < w) {
        const double s0 = sm[w4], s1 = sm[w4 + 1];
        a0r = fma(s0, z0r, a0r); a0i = fma(s0, z0i, a0i);
        a1r = fma(s1, z1r, a1r); a1i = fma(s1, z1i, a1i);
    }
    double yr = (a0r + a1r) + (a2r + a3r);
    double yi = (a0i + a1i) + (a2i + a3i);
    const double scale = 2.381 / (double)((w >> 1) + 1);
    yr *= scale; yi *= scale;
    float ampl = 0.0f, ph = 0.0f;
    if (tid < nhar) {
        ampl = (float)sqrt(yr * yr + yi * yi);
        ph   = (float)atan2(yi, yr);
    }
    out[tid * F + frame] = ampl;
    out[MAX_NHAR * F + tid * F + frame] = ph;
}

extern "C" void kernel_launch(void* const* d_in, const int* in_sizes, int n_in,
                              void* d_out, int out_size, void* d_ws, size_t ws_size,
                              hipStream_t stream) {
    const float* x  = (const float*)d_in[0];
    const float* f0 = (const float*)d_in[1];
    float* out = (float*)d_out;
    const int t = in_sizes[0];
    const int F = in_sizes[1];

    const size_t ccos_b  = (size_t)F * MAX_NHAR * sizeof(double);         // 1 MB
    const size_t parts_b = (size_t)F * SEGS * MAX_NHAR * sizeof(double2); // 16.8 MB
    if (ws_size >= ccos_b + parts_b) {
        double*  ccos  = (double*)d_ws;
        double2* parts = (double2*)((char*)d_ws + ccos_b);
        prep_kernel<<<F, 128, 0, stream>>>(f0, ccos, F);
        goertzel_kernel<<<F * SEGS, 64, 0, stream>>>(x, f0, ccos, parts, t, F);
        finalize_kernel<<<F, 128, 0, stream>>>(f0, parts, out, F);
    } else {
        czt_direct_kernel<<<F, 128, 0, stream>>>(x, f0, out, t, F);
    }
}

// Round 6
// 83.120 us; speedup vs baseline: 1.1074x; 1.0000x over previous
//
#include <hip/hip_runtime.h>

#define HOP 512
#define MAX_NHAR 128
#define N_MAX 4410
#define SEGS 8
#define CHUNK_MAX 552           // pad8(ceil(N_MAX/SEGS)) -- max per-segment span
#define PI_D 3.14159265358979323846

// ---------------------------------------------------------------------------
// Frame-parameter computation (bit-exact vs reference; absmax 0.0 since R1).
// ---------------------------------------------------------------------------
__device__ __forceinline__ void frame_params(double f0v, int& w, int& nhar, double& theta) {
    double f0d = f0v < 40.0 ? 40.0 : f0v;
    const double inv = 44100.0 / f0d;
    nhar = (int)fmin(floor(inv * 0.5), 128.0);
    w = 2 * (int)rint(inv * 2.0);
    if (w > N_MAX) w = N_MAX;
    theta = (2.0 * PI_D * f0d) / 44100.0;
}

__device__ __forceinline__ int chunk8_of(int w) {
    return (((w + SEGS - 1) / SEGS) + 7) & ~7;   // per-segment span, multiple of 8
}

// ---------------------------------------------------------------------------
// Kernel A: cos table C[f][k] = cos(theta_f (k+1)).
// ---------------------------------------------------------------------------
__global__ __launch_bounds__(128) void prep_kernel(
    const float* __restrict__ f0, double* __restrict__ ccos, int F)
{
    const int f = blockIdx.x, k = threadIdx.x;
    int w, nhar; double theta;
    frame_params((double)f0[f], w, nhar, theta);
    ccos[f * MAX_NHAR + k] = cos(theta * (double)(k + 1));
}

// ---------------------------------------------------------------------------
// Kernel B (hot): 128-thread block = 2 INDEPENDENT waves, each owning one
// (frame,segment) and a private LDS half. No __syncthreads: same-wave
// LDS write->read dependencies are compiler-tracked (lgkmcnt).
// Each wave: stage Blackman-windowed samples, then 2-stream real Goertzel
// (harmonics k=lane, k+64 -> each sample broadcast-read ONCE per wave).
// Next 8-sample group is prefetched via ds_read_b128 while the current
// group's fp64 chain executes (hides ~120cyc LDS latency).
// R5 failure mode fixed here: 1-wave blocks capped resident waves (~4/SIMD,
// 20% issue efficiency); 2-wave packing doubles occupancy per workgroup slot.
// fp64 throughout: atan2 branch cut at +/-pi makes fp32 drift a 2*pi fail.
// ---------------------------------------------------------------------------
__global__ __launch_bounds__(128) void goertzel_kernel(
    const float* __restrict__ x, const float* __restrict__ f0,
    const double* __restrict__ ccos, double2* __restrict__ parts,
    int t, int F)
{
    __shared__ double sm[2][CHUNK_MAX];
    const int wave = threadIdx.x >> 6;       // 0..1
    const int lane = threadIdx.x & 63;       // 0..63
    // SEGS=8 -> 4 blocks per frame, 2 segs per block (both segs same frame)
    const int frame = blockIdx.x >> 2;
    const int seg   = ((blockIdx.x & 3) << 1) | wave;

    int w, nhar; double theta;
    frame_params((double)f0[frame], w, nhar, theta);
    const int chunk = chunk8_of(w);
    const int j0 = seg * chunk;
    int lenp = 0;
    if (j0 < w) {
        const int l = w - j0;
        lenp = (l > chunk) ? chunk : ((l + 7) & ~7);   // padded length (x8)
    }

    double* smw = sm[wave];

    // ---- stage Blackman-windowed samples into this wave's LDS half ----
    {
        const double c2pi_invw = (2.0 * PI_D) / (double)w;
        const int base = frame * HOP - (w >> 1) + j0;
        for (int j = lane; j < lenp; j += 64) {
            double outv = 0.0;
            if (j0 + j < w) {
                const int ix = base + j;
                const double val = (ix >= 0 && ix < t) ? (double)x[ix] : 0.0;
                const double c1 = cos(c2pi_invw * (double)(j0 + j));
                // 0.42 - 0.5 c + 0.08 (2c^2-1) = 0.34 - 0.5 c + 0.16 c^2
                const double win = fma(0.16, c1 * c1, 0.34) - 0.5 * c1;
                outv = val * win;
            }
            smw[j] = outv;
        }
    }
    // no barrier: producer == consumer wave; compiler inserts lgkmcnt waits

    // ---- 2-stream Goertzel with software-pipelined LDS reads ----
    const double Ca = 2.0 * ccos[frame * MAX_NHAR + lane];
    const double Cb = 2.0 * ccos[frame * MAX_NHAR + lane + 64];
    double s1a = 0.0, s2a = 0.0, s1b = 0.0, s2b = 0.0;
    const double2* __restrict__ sm2 = (const double2*)smw;   // 16B-aligned, jb%8==0

    if (lenp > 0) {
        double2 c0 = sm2[0], c1 = sm2[1], c2 = sm2[2], c3 = sm2[3];
        if (nhar > 64) {
            for (int jb = 0; jb < lenp; jb += 8) {
                const int nb = (jb + 8 < lenp) ? ((jb + 8) >> 1) : 0;
                const double2 n0 = sm2[nb], n1 = sm2[nb + 1], n2 = sm2[nb + 2], n3 = sm2[nb + 3];
                double xv[8] = {c0.x, c0.y, c1.x, c1.y, c2.x, c2.y, c3.x, c3.y};
                #pragma unroll
                for (int u = 0; u < 8; ++u) {
                    const double ta = xv[u] - s2a;
                    const double tb = xv[u] - s2b;
                    const double na = fma(Ca, s1a, ta);
                    const double nb2 = fma(Cb, s1b, tb);
                    s2a = s1a; s1a = na;
                    s2b = s1b; s1b = nb2;
                }
                c0 = n0; c1 = n1; c2 = n2; c3 = n3;
            }
        } else {
            // harmonics 65..128 all masked for this frame: single stream
            for (int jb = 0; jb < lenp; jb += 8) {
                const int nb = (jb + 8 < lenp) ? ((jb + 8) >> 1) : 0;
                const double2 n0 = sm2[nb], n1 = sm2[nb + 1], n2 = sm2[nb + 2], n3 = sm2[nb + 3];
                double xv[8] = {c0.x, c0.y, c1.x, c1.y, c2.x, c2.y, c3.x, c3.y};
                #pragma unroll
                for (int u = 0; u < 8; ++u) {
                    const double ta = xv[u] - s2a;
                    const double na = fma(Ca, s1a, ta);
                    s2a = s1a; s1a = na;
                }
                c0 = n0; c1 = n1; c2 = n2; c3 = n3;
            }
        }
    }
    double2* p = parts + (size_t)(frame * SEGS + seg) * MAX_NHAR;
    p[lane]      = make_double2(s1a, s2a);
    p[lane + 64] = make_double2(s1b, s2b);   // zeros when single-stream (masked later)
}

// ---------------------------------------------------------------------------
// Kernel C: combine SEGS partials analytically, scale, amp/phase. (R4/R5-verified)
// partial_y(seg) = P (s1 - e^{-iw} s2), P = e^{-iw (j0 + steps - 1)};
// mid segs steps==chunk -> P advances by Q = e^{-iw chunk}; last data seg
// uses the padded end position (endlast).
// ---------------------------------------------------------------------------
__global__ __launch_bounds__(128) void finalize_kernel(
    const float* __restrict__ f0, const double2* __restrict__ parts,
    float* __restrict__ out, int F)
{
    const int frame = blockIdx.x;
    const int tid = threadIdx.x;

    int w, nhar; double theta;
    frame_params((double)f0[frame], w, nhar, theta);
    const int chunk = chunk8_of(w);
    const int slast = (w - 1) / chunk;
    const int endlast = slast * chunk + (((w - slast * chunk) + 7) & ~7);
    const double omega = theta * (double)(tid + 1);

    double sw, cw; sincos(omega, &sw, &cw);                      // e^{-iw} = (cw,-sw)
    double sq, cq; sincos(omega * (double)chunk, &sq, &cq);      // Q = (cq,-sq)
    double sl, cl; sincos(omega * (double)(endlast - 1), &sl, &cl);

    double Rr = cq * cw + sq * sw, Ri = cq * sw - sq * cw;       // e^{-iw(chunk-1)}
    double yr = 0.0, yi = 0.0;
    const double2* p = parts + (size_t)frame * SEGS * MAX_NHAR + tid;
    #pragma unroll
    for (int s = 0; s < SEGS; ++s) {
        const double2 v = p[(size_t)s * MAX_NHAR];
        const double tr = fma(-cw, v.y, v.x);
        const double ti = sw * v.y;
        const double Pr = (s == slast) ? cl : Rr;
        const double Pi = (s == slast) ? -sl : Ri;
        yr = fma(Pr, tr, fma(-Pi, ti, yr));
        yi = fma(Pr, ti, fma( Pi, tr, yi));
        const double nr = Rr * cq + Ri * sq;                     // R *= Q
        Ri = Ri * cq - Rr * sq; Rr = nr;
    }
    const double scale = 2.381 / (double)((w >> 1) + 1);
    yr *= scale; yi *= scale;

    float ampl = 0.0f, ph = 0.0f;
    if (tid < nhar) {
        ampl = (float)sqrt(yr * yr + yi * yi);
        ph   = (float)atan2(yi, yr);
    }
    out[tid * F + frame] = ampl;
    out[MAX_NHAR * F + tid * F + frame] = ph;
}

// ---------------------------------------------------------------------------
// Fallback: single-kernel direct DFT (R1, verified) if ws is too small.
// ---------------------------------------------------------------------------
__global__ __launch_bounds__(128) void czt_direct_kernel(
    const float* __restrict__ x, const float* __restrict__ f0,
    float* __restrict__ out, int t, int F)
{
    __shared__ double sm[N_MAX];
    const int frame = blockIdx.x;
    const int tid = threadIdx.x;
    int w, nhar; double theta;
    frame_params((double)f0[frame], w, nhar, theta);
    {
        const double invw = 1.0 / (double)w;
        double sa, ca, ss, cs;
        sincos((2.0 * PI_D) * ((double)tid * invw), &sa, &ca);
        sincos((2.0 * PI_D) * (128.0 * invw), &ss, &cs);
        double zr = ca, zi = sa;
        const int base = frame * HOP - (w >> 1);
        for (int j = tid; j < w; j += 128) {
            const int ix = base + j;
            const double val = (ix >= 0 && ix < t) ? (double)x[ix] : 0.0;
            const double c = zr;
            const double win = 0.42 - 0.5 * c + 0.08 * (2.0 * c * c - 1.0);
            sm[j] = val * win;
            const double nzr = zr * cs - zi * ss;
            zi = zr * ss + zi * cs;
            zr = nzr;
        }
    }
    __syncthreads();
    double s, c;
    sincos(theta * (double)(tid + 1), &s, &c);
    const double rr = c, ri = -s;
    const double r2r = rr * rr - ri * ri, r2i = 2.0 * rr * ri;
    const double r4r = r2r * r2r - r2i * r2i, r4i = 2.0 * r2r * r2i;
    const double r3r = r2r * rr - r2i * ri, r3i = r2r * ri + r2i * rr;
    double z0r = 1.0, z0i = 0.0, z1r = rr, z1i = ri;
    double z2r = r2r, z2i = r2i, z3r = r3r, z3i = r3i;
    double a0r = 0, a0i = 0, a1r = 0, a1i = 0, a2r = 0, a2i = 0, a3r = 0, a3i = 0;
    const int w4 = w & ~3;
    for (int j = 0; j < w4; j += 4) {
        const double s0 = sm[j], s1 = sm[j + 1], s2 = sm[j + 2], s3 = sm[j + 3];
        double tr;
        a0r = fma(s0, z0r, a0r); a0i = fma(s0, z0i, a0i);
        tr = z0r * r4r - z0i * r4i; z0i = z0r * r4i + z0i * r4r; z0r = tr;
        a1r = fma(s1, z1r, a1r); a1i = fma(s1, z1i, a1i);
        tr = z1r * r4r - z1i * r4i; z1i = z1r * r4i + z1i * r4r; z1r = tr;
        a2r = fma(s2, z2r, a2r); a2i = fma(s2, z2i, a2i);
        tr = z2r * r4r - z2i * r4i; z2i = z2r * r4i + z2i * r4r; z2r = tr;
        a3r = fma(s3, z3r, a3r); a3i = fma(s3, z3i, a3i);
        tr = z3r * r4r - z3i * r4i; z3i = z3r * r4i + z3i * r4r; z3r = tr;
    }
    if (w4 < w) {
        const double s0 = sm[w4], s1 = sm[w4 + 1];
        a0r = fma(s0, z0r, a0r); a0i = fma(s0, z0i, a0i);
        a1r = fma(s1, z1r, a1r); a1i = fma(s1, z1i, a1i);
    }
    double yr = (a0r + a1r) + (a2r + a3r);
    double yi = (a0i + a1i) + (a2i + a3i);
    const double scale = 2.381 / (double)((w >> 1) + 1);
    yr *= scale; yi *= scale;
    float ampl = 0.0f, ph = 0.0f;
    if (tid < nhar) {
        ampl = (float)sqrt(yr * yr + yi * yi);
        ph   = (float)atan2(yi, yr);
    }
    out[tid * F + frame] = ampl;
    out[MAX_NHAR * F + tid * F + frame] = ph;
}

extern "C" void kernel_launch(void* const* d_in, const int* in_sizes, int n_in,
                              void* d_out, int out_size, void* d_ws, size_t ws_size,
                              hipStream_t stream) {
    const float* x  = (const float*)d_in[0];
    const float* f0 = (const float*)d_in[1];
    float* out = (float*)d_out;
    const int t = in_sizes[0];
    const int F = in_sizes[1];

    const size_t ccos_b  = (size_t)F * MAX_NHAR * sizeof(double);         // 1 MB
    const size_t parts_b = (size_t)F * SEGS * MAX_NHAR * sizeof(double2); // 16.8 MB
    if (ws_size >= ccos_b + parts_b) {
        double*  ccos  = (double*)d_ws;
        double2* parts = (double2*)((char*)d_ws + ccos_b);
        prep_kernel<<<F, 128, 0, stream>>>(f0, ccos, F);
        goertzel_kernel<<<F * SEGS / 2, 128, 0, stream>>>(x, f0, ccos, parts, t, F);
        finalize_kernel<<<F, 128, 0, stream>>>(f0, parts, out, F);
    } else {
        czt_direct_kernel<<<F, 128, 0, stream>>>(x, f0, out, t, F);
    }
}

// Round 7
// 76.178 us; speedup vs baseline: 1.2083x; 1.0911x over previous
//
#include <hip/hip_runtime.h>

#define HOP 512
#define MAX_NHAR 128
#define N_MAX 4410
#define SEGS 8
#define SM_N 4424               // N_MAX + 8 zero-pad slots (covers padded last-seg reads)
#define PI_D 3.14159265358979323846

// ---------------------------------------------------------------------------
// Frame-parameter computation (bit-exact vs reference; absmax 0.0 since R1).
// ---------------------------------------------------------------------------
__device__ __forceinline__ void frame_params(double f0v, int& w, int& nhar, double& theta) {
    double f0d = f0v < 40.0 ? 40.0 : f0v;
    const double inv = 44100.0 / f0d;
    nhar = (int)fmin(floor(inv * 0.5), 128.0);
    w = 2 * (int)rint(inv * 2.0);
    if (w > N_MAX) w = N_MAX;
    theta = (2.0 * PI_D * f0d) / 44100.0;
}

// ---------------------------------------------------------------------------
// Fully fused kernel: one block per frame, 512 threads = 8 waves.
//   phase 1: cooperative coalesced staging of the Blackman-windowed frame
//            into LDS (+ zero pad to w+8) + 128-entry cos table (was prep).
//   phase 2: wave s runs the dual-stream real Goertzel (2 fp64 ops/sample/
//            stream, harmonics k=lane & k+64) on segment s of the frame.
//   phase 3: partials pass through LDS (aliased over staging after barrier;
//            was a 16.8 MB HBM round-trip + separate kernel).
//   phase 4: threads 0..127 combine the 8 partials with the verified
//            padded-segment rotation algebra, scale, amp/phase, store.
// R3-R6 lesson: 3 small launches made fixed per-wave overhead + gaps + parts
// traffic dominate; fusion pays the frame prologue once and removes both.
// fp64 throughout: atan2 branch cut at +/-pi makes fp32 drift a 2*pi fail.
// ---------------------------------------------------------------------------
__global__ __launch_bounds__(512, 6) void czt_fused_kernel(
    const float* __restrict__ x, const float* __restrict__ f0,
    float* __restrict__ out, int t, int F)
{
    __shared__ double sm[SM_N];          // staged frame; first 16 KB reused for partials
    __shared__ double cc[MAX_NHAR];      // cos(theta*(k+1))
    const int tid  = threadIdx.x;        // 0..511
    const int wave = tid >> 6;           // 0..7 == segment id
    const int lane = tid & 63;

    const int frame = blockIdx.x;
    int w, nhar; double theta;
    frame_params((double)f0[frame], w, nhar, theta);
    const int chunk = (((w + SEGS - 1) / SEGS) + 7) & ~7;   // per-seg span, x8

    // ---- phase 1: stage windowed frame (coalesced), zero pad, cos table ----
    {
        const double c2pi_invw = (2.0 * PI_D) / (double)w;
        const int base = frame * HOP - (w >> 1);             // pad offset cancels
        for (int j = tid; j < w; j += 512) {
            const int ix = base + j;
            const double val = (ix >= 0 && ix < t) ? (double)x[ix] : 0.0;
            const double c1 = cos(c2pi_invw * (double)j);
            // 0.42 - 0.5 c + 0.08 (2c^2-1) = 0.34 - 0.5 c + 0.16 c^2
            const double win = fma(0.16, c1 * c1, 0.34) - 0.5 * c1;
            sm[j] = val * win;
        }
        if (tid < 8) sm[w + tid] = 0.0;                      // padded last-seg reads
        if (tid < MAX_NHAR) cc[tid] = cos(theta * (double)(tid + 1));
    }
    __syncthreads();

    // ---- phase 2: dual-stream Goertzel on this wave's segment ----
    const int j0 = wave * chunk;
    int lenp = 0;
    if (j0 < w) {
        const int l = w - j0;
        lenp = (l > chunk) ? chunk : ((l + 7) & ~7);         // padded length (x8)
    }
    const double Ca = 2.0 * cc[lane];
    const double Cb = 2.0 * cc[lane + 64];
    double s1a = 0.0, s2a = 0.0, s1b = 0.0, s2b = 0.0;
    const double2* __restrict__ sm2 = (const double2*)(sm + j0);  // j0 x8 -> 16B aligned

    if (nhar > 64) {
        for (int jb = 0; jb < lenp; jb += 8) {
            const int h = jb >> 1;
            const double2 v0 = sm2[h], v1 = sm2[h + 1], v2 = sm2[h + 2], v3 = sm2[h + 3];
            const double xv[8] = {v0.x, v0.y, v1.x, v1.y, v2.x, v2.y, v3.x, v3.y};
            #pragma unroll
            for (int u = 0; u < 8; ++u) {
                const double na = fma(Ca, s1a, xv[u] - s2a);
                const double nb = fma(Cb, s1b, xv[u] - s2b);
                s2a = s1a; s1a = na;
                s2b = s1b; s1b = nb;
            }
        }
    } else {
        // harmonics 65..128 all masked for this frame: single stream
        for (int jb = 0; jb < lenp; jb += 8) {
            const int h = jb >> 1;
            const double2 v0 = sm2[h], v1 = sm2[h + 1], v2 = sm2[h + 2], v3 = sm2[h + 3];
            const double xv[8] = {v0.x, v0.y, v1.x, v1.y, v2.x, v2.y, v3.x, v3.y};
            #pragma unroll
            for (int u = 0; u < 8; ++u) {
                const double na = fma(Ca, s1a, xv[u] - s2a);
                s2a = s1a; s1a = na;
            }
        }
    }
    __syncthreads();                      // all waves done READING sm

    // ---- phase 3: partials through LDS (alias over staging buffer) ----
    double2* parts = (double2*)sm;        // [seg][k] double2: 8*128*16B = 16 KB < SM_N*8
    parts[wave * MAX_NHAR + lane]      = make_double2(s1a, s2a);
    parts[wave * MAX_NHAR + lane + 64] = make_double2(s1b, s2b);  // zeros if 1-stream
    __syncthreads();

    // ---- phase 4: combine (verified R4-R6 finalize algebra), amp/phase ----
    if (tid < MAX_NHAR) {
        const int slast = (w - 1) / chunk;
        const int endlast = slast * chunk + (((w - slast * chunk) + 7) & ~7);
        const double omega = theta * (double)(tid + 1);

        double sw, cw; sincos(omega, &sw, &cw);                  // e^{-iw} = (cw,-sw)
        double sq, cq; sincos(omega * (double)chunk, &sq, &cq);  // Q = (cq,-sq)
        double sl, cl; sincos(omega * (double)(endlast - 1), &sl, &cl);

        double Rr = cq * cw + sq * sw, Ri = cq * sw - sq * cw;   // e^{-iw(chunk-1)}
        double yr = 0.0, yi = 0.0;
        #pragma unroll
        for (int s = 0; s < SEGS; ++s) {
            const double2 v = parts[s * MAX_NHAR + tid];
            const double tr = fma(-cw, v.y, v.x);                // s1 - cw*s2
            const double ti = sw * v.y;                          // + i sw*s2
            const double Pr = (s == slast) ? cl : Rr;
            const double Pi = (s == slast) ? -sl : Ri;
            yr = fma(Pr, tr, fma(-Pi, ti, yr));
            yi = fma(Pr, ti, fma( Pi, tr, yi));
            const double nr = Rr * cq + Ri * sq;                 // R *= Q
            Ri = Ri * cq - Rr * sq; Rr = nr;
        }
        const double scale = 2.381 / (double)((w >> 1) + 1);
        yr *= scale; yi *= scale;

        float ampl = 0.0f, ph = 0.0f;
        if (tid < nhar) {
            ampl = (float)sqrt(yr * yr + yi * yi);
            ph   = (float)atan2(yi, yr);
        }
        out[tid * F + frame] = ampl;                 // ampl  (MAX_NHAR, F)
        out[MAX_NHAR * F + tid * F + frame] = ph;    // phase (MAX_NHAR, F)
    }
}

extern "C" void kernel_launch(void* const* d_in, const int* in_sizes, int n_in,
                              void* d_out, int out_size, void* d_ws, size_t ws_size,
                              hipStream_t stream) {
    const float* x  = (const float*)d_in[0];
    const float* f0 = (const float*)d_in[1];
    float* out = (float*)d_out;
    const int t = in_sizes[0];   // samples
    const int F = in_sizes[1];   // frames
    czt_fused_kernel<<<F, 512, 0, stream>>>(x, f0, out, t, F);
}